// Round 6
// baseline (386.573 us; speedup 1.0000x reference)
//
#include <hip/hip_runtime.h>
#include <hip/hip_bf16.h>

#define NHEADS 16
#define HDIM 64
#define BATCH 4
#define SEQ 2048
#define CDIM 1024
#define ROWS (BATCH * SEQ)  // 8192
// attention scale 1/sqrt(64) folded with log2(e) so attn uses exp2
#define QSCALE (0.125f * 1.44269504088896f)

typedef __attribute__((ext_vector_type(8))) short short8;
typedef __attribute__((ext_vector_type(4))) float f32x4;
typedef __attribute__((ext_vector_type(4))) unsigned int u32x4;
typedef __attribute__((ext_vector_type(2))) unsigned int u32x2;

__device__ inline short f2bf(float f) {
    unsigned int u = __builtin_bit_cast(unsigned int, f);
    unsigned int r = (u + 0x7fffu + ((u >> 16) & 1u)) >> 16;
    return (short)r;
}

__device__ __forceinline__ void gll16(const void* g, void* l) {
    __builtin_amdgcn_global_load_lds(
        (const __attribute__((address_space(1))) unsigned int*)g,
        (__attribute__((address_space(3))) unsigned int*)l, 16, 0, 0);
}

// pack two f32 to bf16x2 (truncate): low = hi16(a), high = hi16(b).
// truncation bias cancels between PV numerator and ones-MFMA denominator.
__device__ __forceinline__ unsigned int pack_bf2(float a, float b) {
    return __builtin_amdgcn_perm(__builtin_bit_cast(unsigned int, b),
                                 __builtin_bit_cast(unsigned int, a), 0x07060302u);
}

// ---------------------------------------------------------------------------
// Pre-pass 1: fp32 -> bf16 elementwise (x1, x2)
// ---------------------------------------------------------------------------
__global__ __launch_bounds__(256) void cvt_bf16(const float* __restrict__ src,
                                                short* __restrict__ dst, int n8) {
    int i = blockIdx.x * 256 + threadIdx.x;
    if (i < n8) {
        f32x4 a = ((const f32x4*)src)[i * 2];
        f32x4 b = ((const f32x4*)src)[i * 2 + 1];
        short8 o;
        o[0] = f2bf(a[0]); o[1] = f2bf(a[1]); o[2] = f2bf(a[2]); o[3] = f2bf(a[3]);
        o[4] = f2bf(b[0]); o[5] = f2bf(b[1]); o[6] = f2bf(b[2]); o[7] = f2bf(b[3]);
        ((short8*)dst)[i] = o;
    }
}

// ---------------------------------------------------------------------------
// Pre-pass 2: W [K=1024][Nw] fp32 -> W^T [Nw][1024] bf16 (64x64 LDS tiles)
// ---------------------------------------------------------------------------
__global__ __launch_bounds__(256) void wtrans(const float* __restrict__ W,
                                              short* __restrict__ WT, int Nw) {
    __shared__ short T[64][72];
    const int t = threadIdx.x;
    const int n0 = blockIdx.x * 64, k0 = blockIdx.y * 64;
    const int kl = t >> 2, c4 = (t & 3) * 16;
    const float* src = W + (size_t)(k0 + kl) * Nw + n0 + c4;
    short8 s0, s1;
#pragma unroll
    for (int e = 0; e < 2; e++) {
        f32x4 u = *(const f32x4*)(src + e * 4);
        s0[e * 4 + 0] = f2bf(u[0]); s0[e * 4 + 1] = f2bf(u[1]);
        s0[e * 4 + 2] = f2bf(u[2]); s0[e * 4 + 3] = f2bf(u[3]);
        f32x4 v = *(const f32x4*)(src + 8 + e * 4);
        s1[e * 4 + 0] = f2bf(v[0]); s1[e * 4 + 1] = f2bf(v[1]);
        s1[e * 4 + 2] = f2bf(v[2]); s1[e * 4 + 3] = f2bf(v[3]);
    }
    *(short8*)&T[kl][c4] = s0;
    *(short8*)&T[kl][c4 + 8] = s1;
    __syncthreads();
#pragma unroll
    for (int pass = 0; pass < 2; pass++) {
        int n = (t >> 3) + pass * 32;
        short8 o;
#pragma unroll
        for (int e = 0; e < 8; e++) o[e] = T[(t & 7) * 8 + e][n];
        *(short8*)(WT + (size_t)(n0 + n) * 1024 + k0 + (t & 7) * 8) = o;
    }
}

// ---------------------------------------------------------------------------
// GEMM (bf16 A, bf16 B^T, fp32 acc) m97-style: 128x128 tile, BK=32,
// global_load_lds staging. Q variant: bias + per-head LayerNorm + QSCALE.
// ---------------------------------------------------------------------------
__global__ __launch_bounds__(256) void gemm_q_ln(
    const short* __restrict__ A,     // [8192][1024] bf16
    const short* __restrict__ BT,    // [1024][1024] bf16 (W^T)
    const float* __restrict__ bias,  // [1024]
    const float* __restrict__ gamma, // [64]
    const float* __restrict__ beta,  // [64]
    short* __restrict__ Out)         // [B][H][N][64] bf16 (pre-scaled)
{
    __shared__ short As[128][32];
    __shared__ short Bs[128][32];

    const int tid = threadIdx.x;
    const int wave = tid >> 6, lane = tid & 63;
    const int wr = wave >> 1, wc = wave & 1;
    const int quad = lane >> 4, l15 = lane & 15;
    const int rblk = blockIdx.y, cblk = blockIdx.x;

    f32x4 acc[4][4];
#pragma unroll
    for (int i = 0; i < 4; i++)
#pragma unroll
        for (int j = 0; j < 4; j++) acc[i][j] = f32x4{0.f, 0.f, 0.f, 0.f};

    const int srow = wave * 32 + (lane >> 2);
    const int scol = (lane & 3) * 8;

    for (int k0 = 0; k0 < CDIM; k0 += 32) {
        __syncthreads();
#pragma unroll
        for (int c = 0; c < 2; c++) {
            gll16(A + (size_t)(rblk * 128 + srow + c * 16) * CDIM + k0 + scol,
                  &As[srow + c * 16][scol]);
            gll16(BT + (size_t)(cblk * 128 + srow + c * 16) * CDIM + k0 + scol,
                  &Bs[srow + c * 16][scol]);
        }
        __syncthreads();

        short8 af[4], bfr[4];
#pragma unroll
        for (int i = 0; i < 4; i++)
            af[i] = *(const short8*)&As[wr * 64 + i * 16 + l15][quad * 8];
#pragma unroll
        for (int j = 0; j < 4; j++)
            bfr[j] = *(const short8*)&Bs[wc * 64 + j * 16 + l15][quad * 8];
#pragma unroll
        for (int i = 0; i < 4; i++)
#pragma unroll
            for (int j = 0; j < 4; j++)
                acc[i][j] = __builtin_amdgcn_mfma_f32_16x16x32_bf16(af[i], bfr[j], acc[i][j], 0, 0, 0);
    }

    const int col0 = cblk * 128 + wc * 64;
    const int h = col0 >> 6;
    float bv[4], gv[4], btv[4];
#pragma unroll
    for (int j = 0; j < 4; j++) {
        int d = j * 16 + l15;
        bv[j] = bias[col0 + d];
        gv[j] = gamma[d];
        btv[j] = beta[d];
    }
#pragma unroll
    for (int i = 0; i < 4; i++) {
        int rowl = rblk * 128 + wr * 64 + i * 16 + quad * 4;
#pragma unroll
        for (int reg = 0; reg < 4; reg++) {
            float x[4], s = 0.f, s2 = 0.f;
#pragma unroll
            for (int j = 0; j < 4; j++) {
                x[j] = acc[i][j][reg] + bv[j];
                s += x[j];
                s2 += x[j] * x[j];
            }
#pragma unroll
            for (int m = 1; m < 16; m <<= 1) {
                s += __shfl_xor(s, m);
                s2 += __shfl_xor(s2, m);
            }
            float mean = s * (1.f / 64.f);
            float var = s2 * (1.f / 64.f) - mean * mean;
            float rstd = rsqrtf(var + 1e-5f);
            int r = rowl + reg;
            int b = r >> 11, n = r & (SEQ - 1);
            size_t base = (((size_t)b * NHEADS + h) * SEQ + n) * 64;
#pragma unroll
            for (int j = 0; j < 4; j++) {
                float y = ((x[j] - mean) * rstd * gv[j] + btv[j]) * QSCALE;
                Out[base + j * 16 + l15] = f2bf(y);
            }
        }
    }
}

// KV variant: cblk<8: K with LN -> [bh][n][d]; cblk>=8: V -> VT [bh][d][n].
__global__ __launch_bounds__(256) void gemm_kv(
    const short* __restrict__ A,     // [8192][1024] bf16
    const short* __restrict__ BT,    // [2048][1024] bf16 (Wkv^T)
    const float* __restrict__ bias,  // [2048]
    const float* __restrict__ gamma, // [64]
    const float* __restrict__ beta,  // [64]
    short* __restrict__ KOut,        // [B][H][N][64] bf16
    short* __restrict__ VT)          // [B][H][64][N] bf16
{
    __shared__ short As[128][32];
    __shared__ short Bs[128][32];
    __shared__ short Ts[4][64][68];

    const int tid = threadIdx.x;
    const int wave = tid >> 6, lane = tid & 63;
    const int wr = wave >> 1, wc = wave & 1;
    const int quad = lane >> 4, l15 = lane & 15;
    const int rblk = blockIdx.y, cblk = blockIdx.x;

    f32x4 acc[4][4];
#pragma unroll
    for (int i = 0; i < 4; i++)
#pragma unroll
        for (int j = 0; j < 4; j++) acc[i][j] = f32x4{0.f, 0.f, 0.f, 0.f};

    const int srow = wave * 32 + (lane >> 2);
    const int scol = (lane & 3) * 8;

    for (int k0 = 0; k0 < CDIM; k0 += 32) {
        __syncthreads();
#pragma unroll
        for (int c = 0; c < 2; c++) {
            gll16(A + (size_t)(rblk * 128 + srow + c * 16) * CDIM + k0 + scol,
                  &As[srow + c * 16][scol]);
            gll16(BT + (size_t)(cblk * 128 + srow + c * 16) * CDIM + k0 + scol,
                  &Bs[srow + c * 16][scol]);
        }
        __syncthreads();

        short8 af[4], bfr[4];
#pragma unroll
        for (int i = 0; i < 4; i++)
            af[i] = *(const short8*)&As[wr * 64 + i * 16 + l15][quad * 8];
#pragma unroll
        for (int j = 0; j < 4; j++)
            bfr[j] = *(const short8*)&Bs[wc * 64 + j * 16 + l15][quad * 8];
#pragma unroll
        for (int i = 0; i < 4; i++)
#pragma unroll
            for (int j = 0; j < 4; j++)
                acc[i][j] = __builtin_amdgcn_mfma_f32_16x16x32_bf16(af[i], bfr[j], acc[i][j], 0, 0, 0);
    }

    const int col0 = cblk * 128 + wc * 64;
    const int g = col0 >> 6;
    float bv[4];
#pragma unroll
    for (int j = 0; j < 4; j++) bv[j] = bias[col0 + j * 16 + l15];

    if (g < NHEADS) {  // K path with LayerNorm
        const int h = g;
        float gv[4], btv[4];
#pragma unroll
        for (int j = 0; j < 4; j++) {
            int d = j * 16 + l15;
            gv[j] = gamma[d];
            btv[j] = beta[d];
        }
#pragma unroll
        for (int i = 0; i < 4; i++) {
            int rowl = rblk * 128 + wr * 64 + i * 16 + quad * 4;
#pragma unroll
            for (int reg = 0; reg < 4; reg++) {
                float x[4], s = 0.f, s2 = 0.f;
#pragma unroll
                for (int j = 0; j < 4; j++) {
                    x[j] = acc[i][j][reg] + bv[j];
                    s += x[j];
                    s2 += x[j] * x[j];
                }
#pragma unroll
                for (int m = 1; m < 16; m <<= 1) {
                    s += __shfl_xor(s, m);
                    s2 += __shfl_xor(s2, m);
                }
                float mean = s * (1.f / 64.f);
                float var = s2 * (1.f / 64.f) - mean * mean;
                float rstd = rsqrtf(var + 1e-5f);
                int r = rowl + reg;
                int b = r >> 11, n = r & (SEQ - 1);
                size_t base = (((size_t)b * NHEADS + h) * SEQ + n) * 64;
#pragma unroll
                for (int j = 0; j < 4; j++) {
                    float y = (x[j] - mean) * rstd * gv[j] + btv[j];
                    KOut[base + j * 16 + l15] = f2bf(y);
                }
            }
        }
    } else {  // V path: bias -> wave-local transpose -> VT coalesced
        const int h = g - NHEADS;
#pragma unroll
        for (int i = 0; i < 4; i++)
#pragma unroll
            for (int reg = 0; reg < 4; reg++)
#pragma unroll
                for (int j = 0; j < 4; j++)
                    Ts[wave][i * 16 + quad * 4 + reg][j * 16 + l15] =
                        f2bf(acc[i][j][reg] + bv[j]);
        const int r = rblk * 128 + wr * 64 + lane;
        const int b = r >> 11, n = r & (SEQ - 1);
        const size_t vtbase = (((size_t)b * NHEADS + h) * 64) * SEQ;
#pragma unroll
        for (int e8 = 0; e8 < 8; e8++) {
            short8 v = *(const short8*)&Ts[wave][lane][e8 * 8];
#pragma unroll
            for (int e = 0; e < 8; e++)
                VT[vtbase + (size_t)(e8 * 8 + e) * SEQ + n] = v[e];
        }
    }
}

// ---------------------------------------------------------------------------
// Flash attention v5: v4 loop + (a) __launch_bounds__(256,2) so all state
// fits in 256 VGPRs (R5's 160 MiB WRITE_SIZE was scratch spill at 108 VGPRs),
// (b) grid swapped to (bh, qt) so the 32 q-tile blocks of one bh differ by
// 64 in linear dispatch ID -> same XCD (round-robin %8) -> K/V L2-resident.
// ---------------------------------------------------------------------------
__global__ __launch_bounds__(256, 2) void attn_fa(
    const short* __restrict__ Q,   // [B][H][N][64] bf16, pre-scaled QSCALE
    const short* __restrict__ Kk,  // [B][H][N][64] bf16
    const short* __restrict__ VT,  // [B][H][64][N] bf16
    float* __restrict__ Out)       // [B][N][1024] fp32
{
    __shared__ __align__(16) char smem_raw[20480];

    const int tid = threadIdx.x;
    const int w = tid >> 6, lane = tid & 63;
    const int q = lane >> 4, l15 = lane & 15;
    const int bh = blockIdx.x;   // swapped: same-bh blocks land on one XCD
    const int b = bh >> 4, h = bh & 15;
    const int qt = blockIdx.y;
    const size_t hb = (size_t)bh * SEQ * 64;
    const size_t vb = (size_t)bh * 64 * SEQ;

    unsigned int* Pd = (unsigned int*)smem_raw + w * 1280;  // [64][20] dwords
    float* Ot = (float*)smem_raw;                           // [64][68]
    float* Lred = (float*)smem_raw + 64 * 68;               // [4][64]

    // Q B-frags: B[k=d][n=qrow]; lane: d = q*8+j (+32*dh), qrow = qc*16+l15
    short8 qf[4][2];
#pragma unroll
    for (int qc = 0; qc < 4; qc++)
#pragma unroll
        for (int dh = 0; dh < 2; dh++)
            qf[qc][dh] = *(const short8*)(Q + hb +
                (size_t)(qt * 64 + qc * 16 + l15) * 64 + dh * 32 + q * 8);

    short8 ones;
#pragma unroll
    for (int e = 0; e < 8; e++) ones[e] = (short)0x3F80;

    f32x4 o[4][4];   // [jd][qc] O^T partials over this wave's keys
#pragma unroll
    for (int jd = 0; jd < 4; jd++)
#pragma unroll
        for (int qc = 0; qc < 4; qc++) o[jd][qc] = f32x4{0.f, 0.f, 0.f, 0.f};
    f32x4 osum[4];
#pragma unroll
    for (int qc = 0; qc < 4; qc++) osum[qc] = f32x4{0.f, 0.f, 0.f, 0.f};

    // K A-frag: key = kti*128 + w*32 + kt*16 + l15, d = dh*32 + q*8
    const short* kbase = Kk + hb + (size_t)(w * 32 + l15) * 64 + q * 8;
    // V A-frag: d = jd*16 + l15, key = kti*128 + w*32 + q*8
    const short* vbase = VT + vb + (size_t)l15 * SEQ + w * 32 + q * 8;

    for (int kti = 0; kti < 16; kti++) {
        short8 kf[2][2];
#pragma unroll
        for (int kt = 0; kt < 2; kt++)
#pragma unroll
            for (int dh = 0; dh < 2; dh++)
                kf[kt][dh] = *(const short8*)(kbase +
                    (size_t)(kti * 128 + kt * 16) * 64 + dh * 32);
        short8 vf[4];
#pragma unroll
        for (int jd = 0; jd < 4; jd++)
            vf[jd] = *(const short8*)(vbase + (size_t)(jd * 16) * SEQ + kti * 128);

        // S^T tile -> exp2 -> pack -> Pd (immediate, short liveness)
#pragma unroll
        for (int kt = 0; kt < 2; kt++)
#pragma unroll
            for (int qc = 0; qc < 4; qc++) {
                f32x4 z = f32x4{0.f, 0.f, 0.f, 0.f};
                z = __builtin_amdgcn_mfma_f32_16x16x32_bf16(kf[kt][0], qf[qc][0], z, 0, 0, 0);
                z = __builtin_amdgcn_mfma_f32_16x16x32_bf16(kf[kt][1], qf[qc][1], z, 0, 0, 0);
                u32x2 d2;
                d2[0] = pack_bf2(__builtin_amdgcn_exp2f(z[0]), __builtin_amdgcn_exp2f(z[1]));
                d2[1] = pack_bf2(__builtin_amdgcn_exp2f(z[2]), __builtin_amdgcn_exp2f(z[3]));
                *(u32x2*)&Pd[(qc * 16 + l15) * 20 + kt * 8 + 2 * q] = d2;
            }

        // P B-frags: keys q*8..q*8+7 at qrow qc*16+l15 (wave-local round trip)
        short8 pf[4];
#pragma unroll
        for (int qc = 0; qc < 4; qc++) {
            u32x4 pr = *(const u32x4*)&Pd[(qc * 16 + l15) * 20 + 4 * q];
            pf[qc] = __builtin_bit_cast(short8, pr);
        }

#pragma unroll
        for (int qc = 0; qc < 4; qc++)
            osum[qc] = __builtin_amdgcn_mfma_f32_16x16x32_bf16(ones, pf[qc], osum[qc], 0, 0, 0);
#pragma unroll
        for (int jd = 0; jd < 4; jd++)
#pragma unroll
            for (int qc = 0; qc < 4; qc++)
                o[jd][qc] = __builtin_amdgcn_mfma_f32_16x16x32_bf16(vf[jd], pf[qc], o[jd][qc], 0, 0, 0);
    }

    // ---- epilogue: phase-accumulate O^T into Ot (aliases Pd), then store ----
    __syncthreads();  // Pd dead everywhere
#pragma unroll
    for (int p = 0; p < 4; p++) {
        int jd = (w + p) & 3;
#pragma unroll
        for (int qc = 0; qc < 4; qc++)
#pragma unroll
            for (int reg = 0; reg < 4; reg++) {
                float* dst = &Ot[(qc * 16 + l15) * 68 + jd * 16 + q * 4 + reg];
                if (p == 0) *dst = o[jd][qc][reg];
                else        *dst += o[jd][qc][reg];
            }
        if (p == 0 && q == 0) {
#pragma unroll
            for (int qc = 0; qc < 4; qc++)
                Lred[w * 64 + qc * 16 + l15] = osum[qc][0];
        }
        __syncthreads();
    }

    // coalesced store: 4 lanes cover one row's 16 floats each -> 64 B lines
    const int row = tid >> 2, c = tid & 3;
    float l = Lred[row] + Lred[64 + row] + Lred[128 + row] + Lred[192 + row];
    float inv = 1.f / l;
    float* obase = Out + ((size_t)b * SEQ + qt * 64 + row) * CDIM + h * 64;
#pragma unroll
    for (int i = 0; i < 4; i++) {
        f32x4 t = *(const f32x4*)&Ot[row * 68 + (c + 4 * i) * 4];
        *(f32x4*)(obase + (c + 4 * i) * 4) = t * inv;
    }
}

extern "C" void kernel_launch(void* const* d_in, const int* in_sizes, int n_in,
                              void* d_out, int out_size, void* d_ws, size_t ws_size,
                              hipStream_t stream) {
    const float* x1 = (const float*)d_in[0];
    const float* x2 = (const float*)d_in[1];
    const float* wq = (const float*)d_in[2];
    const float* bq = (const float*)d_in[3];
    const float* wkv = (const float*)d_in[4];
    const float* bkv = (const float*)d_in[5];
    const float* gq = (const float*)d_in[6];
    const float* btq = (const float*)d_in[7];
    const float* gk = (const float*)d_in[8];
    const float* btk = (const float*)d_in[9];
    float* out = (float*)d_out;

    short* a1 = (short*)d_ws;                          // [8192][1024] bf16
    short* a2 = a1 + (size_t)ROWS * CDIM;
    short* wqT = a2 + (size_t)ROWS * CDIM;             // [1024][1024]
    short* wkvT = wqT + (size_t)CDIM * CDIM;           // [2048][1024]
    short* qln = wkvT + (size_t)2 * CDIM * CDIM;       // [B][H][N][64]
    short* kln = qln + (size_t)ROWS * CDIM;            // [B][H][N][64]
    short* vt = kln + (size_t)ROWS * CDIM;             // [B][H][64][N]

    const int n8 = ROWS * CDIM / 8;
    cvt_bf16<<<dim3(n8 / 256), 256, 0, stream>>>(x1, a1, n8);
    cvt_bf16<<<dim3(n8 / 256), 256, 0, stream>>>(x2, a2, n8);
    wtrans<<<dim3(16, 16), 256, 0, stream>>>(wq, wqT, CDIM);
    wtrans<<<dim3(32, 16), 256, 0, stream>>>(wkv, wkvT, 2 * CDIM);

    gemm_q_ln<<<dim3(8, 64), 256, 0, stream>>>(a1, wqT, bq, gq, btq, qln);
    gemm_kv<<<dim3(16, 64), 256, 0, stream>>>(a2, wkvT, bkv, gk, btk, kln, vt);
    attn_fa<<<dim3(64, 32), 256, 0, stream>>>(qln, kln, vt, out);
}

// Round 7
// 349.360 us; speedup vs baseline: 1.1065x; 1.1065x over previous
//
#include <hip/hip_runtime.h>
#include <hip/hip_bf16.h>

#define NHEADS 16
#define HDIM 64
#define BATCH 4
#define SEQ 2048
#define CDIM 1024
#define ROWS (BATCH * SEQ)  // 8192
// attention scale 1/sqrt(64) folded with log2(e) so attn uses exp2
#define QSCALE (0.125f * 1.44269504088896f)

typedef __attribute__((ext_vector_type(8))) short short8;
typedef __attribute__((ext_vector_type(4))) float f32x4;
typedef __attribute__((ext_vector_type(4))) unsigned int u32x4;
typedef __attribute__((ext_vector_type(2))) unsigned int u32x2;

__device__ inline short f2bf(float f) {
    unsigned int u = __builtin_bit_cast(unsigned int, f);
    unsigned int r = (u + 0x7fffu + ((u >> 16) & 1u)) >> 16;
    return (short)r;
}

__device__ __forceinline__ void gll16(const void* g, void* l) {
    __builtin_amdgcn_global_load_lds(
        (const __attribute__((address_space(1))) unsigned int*)g,
        (__attribute__((address_space(3))) unsigned int*)l, 16, 0, 0);
}

// pack two f32 to bf16x2 (truncate): low = hi16(a), high = hi16(b).
// truncation bias cancels between PV numerator and ones-MFMA denominator.
__device__ __forceinline__ unsigned int pack_bf2(float a, float b) {
    return __builtin_amdgcn_perm(__builtin_bit_cast(unsigned int, b),
                                 __builtin_bit_cast(unsigned int, a), 0x07060302u);
}

// ---------------------------------------------------------------------------
// Pre-pass 1: fp32 -> bf16 elementwise (x1, x2)
// ---------------------------------------------------------------------------
__global__ __launch_bounds__(256) void cvt_bf16(const float* __restrict__ src,
                                                short* __restrict__ dst, int n8) {
    int i = blockIdx.x * 256 + threadIdx.x;
    if (i < n8) {
        f32x4 a = ((const f32x4*)src)[i * 2];
        f32x4 b = ((const f32x4*)src)[i * 2 + 1];
        short8 o;
        o[0] = f2bf(a[0]); o[1] = f2bf(a[1]); o[2] = f2bf(a[2]); o[3] = f2bf(a[3]);
        o[4] = f2bf(b[0]); o[5] = f2bf(b[1]); o[6] = f2bf(b[2]); o[7] = f2bf(b[3]);
        ((short8*)dst)[i] = o;
    }
}

// ---------------------------------------------------------------------------
// Pre-pass 2: W [K=1024][Nw] fp32 -> W^T [Nw][1024] bf16 (64x64 LDS tiles)
// ---------------------------------------------------------------------------
__global__ __launch_bounds__(256) void wtrans(const float* __restrict__ W,
                                              short* __restrict__ WT, int Nw) {
    __shared__ short T[64][72];
    const int t = threadIdx.x;
    const int n0 = blockIdx.x * 64, k0 = blockIdx.y * 64;
    const int kl = t >> 2, c4 = (t & 3) * 16;
    const float* src = W + (size_t)(k0 + kl) * Nw + n0 + c4;
    short8 s0, s1;
#pragma unroll
    for (int e = 0; e < 2; e++) {
        f32x4 u = *(const f32x4*)(src + e * 4);
        s0[e * 4 + 0] = f2bf(u[0]); s0[e * 4 + 1] = f2bf(u[1]);
        s0[e * 4 + 2] = f2bf(u[2]); s0[e * 4 + 3] = f2bf(u[3]);
        f32x4 v = *(const f32x4*)(src + 8 + e * 4);
        s1[e * 4 + 0] = f2bf(v[0]); s1[e * 4 + 1] = f2bf(v[1]);
        s1[e * 4 + 2] = f2bf(v[2]); s1[e * 4 + 3] = f2bf(v[3]);
    }
    *(short8*)&T[kl][c4] = s0;
    *(short8*)&T[kl][c4 + 8] = s1;
    __syncthreads();
#pragma unroll
    for (int pass = 0; pass < 2; pass++) {
        int n = (t >> 3) + pass * 32;
        short8 o;
#pragma unroll
        for (int e = 0; e < 8; e++) o[e] = T[(t & 7) * 8 + e][n];
        *(short8*)(WT + (size_t)(n0 + n) * 1024 + k0 + (t & 7) * 8) = o;
    }
}

// ---------------------------------------------------------------------------
// GEMM (bf16 A, bf16 B^T, fp32 acc) m97-style: 128x128 tile, BK=32,
// global_load_lds staging. Q variant: bias + per-head LayerNorm + QSCALE.
// ---------------------------------------------------------------------------
__global__ __launch_bounds__(256) void gemm_q_ln(
    const short* __restrict__ A,     // [8192][1024] bf16
    const short* __restrict__ BT,    // [1024][1024] bf16 (W^T)
    const float* __restrict__ bias,  // [1024]
    const float* __restrict__ gamma, // [64]
    const float* __restrict__ beta,  // [64]
    short* __restrict__ Out)         // [B][H][N][64] bf16 (pre-scaled)
{
    __shared__ short As[128][32];
    __shared__ short Bs[128][32];

    const int tid = threadIdx.x;
    const int wave = tid >> 6, lane = tid & 63;
    const int wr = wave >> 1, wc = wave & 1;
    const int quad = lane >> 4, l15 = lane & 15;
    const int rblk = blockIdx.y, cblk = blockIdx.x;

    f32x4 acc[4][4];
#pragma unroll
    for (int i = 0; i < 4; i++)
#pragma unroll
        for (int j = 0; j < 4; j++) acc[i][j] = f32x4{0.f, 0.f, 0.f, 0.f};

    const int srow = wave * 32 + (lane >> 2);
    const int scol = (lane & 3) * 8;

    for (int k0 = 0; k0 < CDIM; k0 += 32) {
        __syncthreads();
#pragma unroll
        for (int c = 0; c < 2; c++) {
            gll16(A + (size_t)(rblk * 128 + srow + c * 16) * CDIM + k0 + scol,
                  &As[srow + c * 16][scol]);
            gll16(BT + (size_t)(cblk * 128 + srow + c * 16) * CDIM + k0 + scol,
                  &Bs[srow + c * 16][scol]);
        }
        __syncthreads();

        short8 af[4], bfr[4];
#pragma unroll
        for (int i = 0; i < 4; i++)
            af[i] = *(const short8*)&As[wr * 64 + i * 16 + l15][quad * 8];
#pragma unroll
        for (int j = 0; j < 4; j++)
            bfr[j] = *(const short8*)&Bs[wc * 64 + j * 16 + l15][quad * 8];
#pragma unroll
        for (int i = 0; i < 4; i++)
#pragma unroll
            for (int j = 0; j < 4; j++)
                acc[i][j] = __builtin_amdgcn_mfma_f32_16x16x32_bf16(af[i], bfr[j], acc[i][j], 0, 0, 0);
    }

    const int col0 = cblk * 128 + wc * 64;
    const int h = col0 >> 6;
    float bv[4], gv[4], btv[4];
#pragma unroll
    for (int j = 0; j < 4; j++) {
        int d = j * 16 + l15;
        bv[j] = bias[col0 + d];
        gv[j] = gamma[d];
        btv[j] = beta[d];
    }
#pragma unroll
    for (int i = 0; i < 4; i++) {
        int rowl = rblk * 128 + wr * 64 + i * 16 + quad * 4;
#pragma unroll
        for (int reg = 0; reg < 4; reg++) {
            float x[4], s = 0.f, s2 = 0.f;
#pragma unroll
            for (int j = 0; j < 4; j++) {
                x[j] = acc[i][j][reg] + bv[j];
                s += x[j];
                s2 += x[j] * x[j];
            }
#pragma unroll
            for (int m = 1; m < 16; m <<= 1) {
                s += __shfl_xor(s, m);
                s2 += __shfl_xor(s2, m);
            }
            float mean = s * (1.f / 64.f);
            float var = s2 * (1.f / 64.f) - mean * mean;
            float rstd = rsqrtf(var + 1e-5f);
            int r = rowl + reg;
            int b = r >> 11, n = r & (SEQ - 1);
            size_t base = (((size_t)b * NHEADS + h) * SEQ + n) * 64;
#pragma unroll
            for (int j = 0; j < 4; j++) {
                float y = ((x[j] - mean) * rstd * gv[j] + btv[j]) * QSCALE;
                Out[base + j * 16 + l15] = f2bf(y);
            }
        }
    }
}

// KV variant: cblk<8: K with LN -> [bh][n][d]; cblk>=8: V -> VT [bh][d][n].
__global__ __launch_bounds__(256) void gemm_kv(
    const short* __restrict__ A,     // [8192][1024] bf16
    const short* __restrict__ BT,    // [2048][1024] bf16 (Wkv^T)
    const float* __restrict__ bias,  // [2048]
    const float* __restrict__ gamma, // [64]
    const float* __restrict__ beta,  // [64]
    short* __restrict__ KOut,        // [B][H][N][64] bf16
    short* __restrict__ VT)          // [B][H][64][N] bf16
{
    __shared__ short As[128][32];
    __shared__ short Bs[128][32];
    __shared__ short Ts[4][64][68];

    const int tid = threadIdx.x;
    const int wave = tid >> 6, lane = tid & 63;
    const int wr = wave >> 1, wc = wave & 1;
    const int quad = lane >> 4, l15 = lane & 15;
    const int rblk = blockIdx.y, cblk = blockIdx.x;

    f32x4 acc[4][4];
#pragma unroll
    for (int i = 0; i < 4; i++)
#pragma unroll
        for (int j = 0; j < 4; j++) acc[i][j] = f32x4{0.f, 0.f, 0.f, 0.f};

    const int srow = wave * 32 + (lane >> 2);
    const int scol = (lane & 3) * 8;

    for (int k0 = 0; k0 < CDIM; k0 += 32) {
        __syncthreads();
#pragma unroll
        for (int c = 0; c < 2; c++) {
            gll16(A + (size_t)(rblk * 128 + srow + c * 16) * CDIM + k0 + scol,
                  &As[srow + c * 16][scol]);
            gll16(BT + (size_t)(cblk * 128 + srow + c * 16) * CDIM + k0 + scol,
                  &Bs[srow + c * 16][scol]);
        }
        __syncthreads();

        short8 af[4], bfr[4];
#pragma unroll
        for (int i = 0; i < 4; i++)
            af[i] = *(const short8*)&As[wr * 64 + i * 16 + l15][quad * 8];
#pragma unroll
        for (int j = 0; j < 4; j++)
            bfr[j] = *(const short8*)&Bs[wc * 64 + j * 16 + l15][quad * 8];
#pragma unroll
        for (int i = 0; i < 4; i++)
#pragma unroll
            for (int j = 0; j < 4; j++)
                acc[i][j] = __builtin_amdgcn_mfma_f32_16x16x32_bf16(af[i], bfr[j], acc[i][j], 0, 0, 0);
    }

    const int col0 = cblk * 128 + wc * 64;
    const int g = col0 >> 6;
    float bv[4];
#pragma unroll
    for (int j = 0; j < 4; j++) bv[j] = bias[col0 + j * 16 + l15];

    if (g < NHEADS) {  // K path with LayerNorm
        const int h = g;
        float gv[4], btv[4];
#pragma unroll
        for (int j = 0; j < 4; j++) {
            int d = j * 16 + l15;
            gv[j] = gamma[d];
            btv[j] = beta[d];
        }
#pragma unroll
        for (int i = 0; i < 4; i++) {
            int rowl = rblk * 128 + wr * 64 + i * 16 + quad * 4;
#pragma unroll
            for (int reg = 0; reg < 4; reg++) {
                float x[4], s = 0.f, s2 = 0.f;
#pragma unroll
                for (int j = 0; j < 4; j++) {
                    x[j] = acc[i][j][reg] + bv[j];
                    s += x[j];
                    s2 += x[j] * x[j];
                }
#pragma unroll
                for (int m = 1; m < 16; m <<= 1) {
                    s += __shfl_xor(s, m);
                    s2 += __shfl_xor(s2, m);
                }
                float mean = s * (1.f / 64.f);
                float var = s2 * (1.f / 64.f) - mean * mean;
                float rstd = rsqrtf(var + 1e-5f);
                int r = rowl + reg;
                int b = r >> 11, n = r & (SEQ - 1);
                size_t base = (((size_t)b * NHEADS + h) * SEQ + n) * 64;
#pragma unroll
                for (int j = 0; j < 4; j++) {
                    float y = (x[j] - mean) * rstd * gv[j] + btv[j];
                    KOut[base + j * 16 + l15] = f2bf(y);
                }
            }
        }
    } else {  // V path: bias -> wave-local transpose -> VT coalesced
        const int h = g - NHEADS;
#pragma unroll
        for (int i = 0; i < 4; i++)
#pragma unroll
            for (int reg = 0; reg < 4; reg++)
#pragma unroll
                for (int j = 0; j < 4; j++)
                    Ts[wave][i * 16 + quad * 4 + reg][j * 16 + l15] =
                        f2bf(acc[i][j][reg] + bv[j]);
        const int r = rblk * 128 + wr * 64 + lane;
        const int b = r >> 11, n = r & (SEQ - 1);
        const size_t vtbase = (((size_t)b * NHEADS + h) * 64) * SEQ;
#pragma unroll
        for (int e8 = 0; e8 < 8; e8++) {
            short8 v = *(const short8*)&Ts[wave][lane][e8 * 8];
#pragma unroll
            for (int e = 0; e < 8; e++)
                VT[vtbase + (size_t)(e8 * 8 + e) * SEQ + n] = v[e];
        }
    }
}

// Band store with COMPILE-TIME jd index: keeps o[][] in registers (dynamic
// indexing demotes the whole array to scratch -> R5/R6's 160 MiB WRITE_SIZE).
template <int JD, bool FIRST>
__device__ __forceinline__ void band_store(float* __restrict__ Ot,
                                           const f32x4 (&o)[4][4],
                                           int l15, int q) {
#pragma unroll
    for (int qc = 0; qc < 4; qc++)
#pragma unroll
        for (int reg = 0; reg < 4; reg++) {
            float* dst = &Ot[(qc * 16 + l15) * 68 + JD * 16 + q * 4 + reg];
            if (FIRST) *dst = o[JD][qc][reg];
            else       *dst += o[JD][qc][reg];
        }
}

// ---------------------------------------------------------------------------
// Flash attention v6: v4 loop; epilogue uses constant-index band stores via
// wave-uniform switch (no scratch demotion). Grid (bh, qt) keeps same-bh
// blocks on one XCD for K/V L2 residency.
// ---------------------------------------------------------------------------
__global__ __launch_bounds__(256, 2) void attn_fa(
    const short* __restrict__ Q,   // [B][H][N][64] bf16, pre-scaled QSCALE
    const short* __restrict__ Kk,  // [B][H][N][64] bf16
    const short* __restrict__ VT,  // [B][H][64][N] bf16
    float* __restrict__ Out)       // [B][N][1024] fp32
{
    __shared__ __align__(16) char smem_raw[20480];

    const int tid = threadIdx.x;
    const int w = tid >> 6, lane = tid & 63;
    const int q = lane >> 4, l15 = lane & 15;
    const int bh = blockIdx.x;   // same-bh blocks land on one XCD
    const int b = bh >> 4, h = bh & 15;
    const int qt = blockIdx.y;
    const size_t hb = (size_t)bh * SEQ * 64;
    const size_t vb = (size_t)bh * 64 * SEQ;

    unsigned int* Pd = (unsigned int*)smem_raw + w * 1280;  // [64][20] dwords
    float* Ot = (float*)smem_raw;                           // [64][68]
    float* Lred = (float*)smem_raw + 64 * 68;               // [4][64]

    // Q B-frags: B[k=d][n=qrow]; lane: d = q*8+j (+32*dh), qrow = qc*16+l15
    short8 qf[4][2];
#pragma unroll
    for (int qc = 0; qc < 4; qc++)
#pragma unroll
        for (int dh = 0; dh < 2; dh++)
            qf[qc][dh] = *(const short8*)(Q + hb +
                (size_t)(qt * 64 + qc * 16 + l15) * 64 + dh * 32 + q * 8);

    short8 ones;
#pragma unroll
    for (int e = 0; e < 8; e++) ones[e] = (short)0x3F80;

    f32x4 o[4][4];   // [jd][qc] O^T partials over this wave's keys
#pragma unroll
    for (int jd = 0; jd < 4; jd++)
#pragma unroll
        for (int qc = 0; qc < 4; qc++) o[jd][qc] = f32x4{0.f, 0.f, 0.f, 0.f};
    f32x4 osum[4];
#pragma unroll
    for (int qc = 0; qc < 4; qc++) osum[qc] = f32x4{0.f, 0.f, 0.f, 0.f};

    // K A-frag: key = kti*128 + w*32 + kt*16 + l15, d = dh*32 + q*8
    const short* kbase = Kk + hb + (size_t)(w * 32 + l15) * 64 + q * 8;
    // V A-frag: d = jd*16 + l15, key = kti*128 + w*32 + q*8
    const short* vbase = VT + vb + (size_t)l15 * SEQ + w * 32 + q * 8;

    for (int kti = 0; kti < 16; kti++) {
        short8 kf[2][2];
#pragma unroll
        for (int kt = 0; kt < 2; kt++)
#pragma unroll
            for (int dh = 0; dh < 2; dh++)
                kf[kt][dh] = *(const short8*)(kbase +
                    (size_t)(kti * 128 + kt * 16) * 64 + dh * 32);
        short8 vf[4];
#pragma unroll
        for (int jd = 0; jd < 4; jd++)
            vf[jd] = *(const short8*)(vbase + (size_t)(jd * 16) * SEQ + kti * 128);

        // S^T tile -> exp2 -> pack -> Pd (immediate, short liveness)
#pragma unroll
        for (int kt = 0; kt < 2; kt++)
#pragma unroll
            for (int qc = 0; qc < 4; qc++) {
                f32x4 z = f32x4{0.f, 0.f, 0.f, 0.f};
                z = __builtin_amdgcn_mfma_f32_16x16x32_bf16(kf[kt][0], qf[qc][0], z, 0, 0, 0);
                z = __builtin_amdgcn_mfma_f32_16x16x32_bf16(kf[kt][1], qf[qc][1], z, 0, 0, 0);
                u32x2 d2;
                d2[0] = pack_bf2(__builtin_amdgcn_exp2f(z[0]), __builtin_amdgcn_exp2f(z[1]));
                d2[1] = pack_bf2(__builtin_amdgcn_exp2f(z[2]), __builtin_amdgcn_exp2f(z[3]));
                *(u32x2*)&Pd[(qc * 16 + l15) * 20 + kt * 8 + 2 * q] = d2;
            }

        // P B-frags: keys q*8..q*8+7 at qrow qc*16+l15 (wave-local round trip)
        short8 pf[4];
#pragma unroll
        for (int qc = 0; qc < 4; qc++) {
            u32x4 pr = *(const u32x4*)&Pd[(qc * 16 + l15) * 20 + 4 * q];
            pf[qc] = __builtin_bit_cast(short8, pr);
        }

#pragma unroll
        for (int qc = 0; qc < 4; qc++)
            osum[qc] = __builtin_amdgcn_mfma_f32_16x16x32_bf16(ones, pf[qc], osum[qc], 0, 0, 0);
#pragma unroll
        for (int jd = 0; jd < 4; jd++)
#pragma unroll
            for (int qc = 0; qc < 4; qc++)
                o[jd][qc] = __builtin_amdgcn_mfma_f32_16x16x32_bf16(vf[jd], pf[qc], o[jd][qc], 0, 0, 0);
    }

    // ---- epilogue: phase-accumulate O^T into Ot (aliases Pd), then store ----
    __syncthreads();  // Pd dead everywhere
#pragma unroll
    for (int p = 0; p < 4; p++) {
        const int jd = (w + p) & 3;
        if (p == 0) {
            switch (jd) {
            case 0: band_store<0, true>(Ot, o, l15, q); break;
            case 1: band_store<1, true>(Ot, o, l15, q); break;
            case 2: band_store<2, true>(Ot, o, l15, q); break;
            case 3: band_store<3, true>(Ot, o, l15, q); break;
            }
            if (q == 0) {
#pragma unroll
                for (int qc = 0; qc < 4; qc++)
                    Lred[w * 64 + qc * 16 + l15] = osum[qc][0];
            }
        } else {
            switch (jd) {
            case 0: band_store<0, false>(Ot, o, l15, q); break;
            case 1: band_store<1, false>(Ot, o, l15, q); break;
            case 2: band_store<2, false>(Ot, o, l15, q); break;
            case 3: band_store<3, false>(Ot, o, l15, q); break;
            }
        }
        __syncthreads();
    }

    // coalesced store: 4 lanes cover one row's 16 floats each -> 64 B lines
    const int row = tid >> 2, c = tid & 3;
    float l = Lred[row] + Lred[64 + row] + Lred[128 + row] + Lred[192 + row];
    float inv = 1.f / l;
    float* obase = Out + ((size_t)b * SEQ + qt * 64 + row) * CDIM + h * 64;
#pragma unroll
    for (int i = 0; i < 4; i++) {
        f32x4 t = *(const f32x4*)&Ot[row * 68 + (c + 4 * i) * 4];
        *(f32x4*)(obase + (c + 4 * i) * 4) = t * inv;
    }
}

extern "C" void kernel_launch(void* const* d_in, const int* in_sizes, int n_in,
                              void* d_out, int out_size, void* d_ws, size_t ws_size,
                              hipStream_t stream) {
    const float* x1 = (const float*)d_in[0];
    const float* x2 = (const float*)d_in[1];
    const float* wq = (const float*)d_in[2];
    const float* bq = (const float*)d_in[3];
    const float* wkv = (const float*)d_in[4];
    const float* bkv = (const float*)d_in[5];
    const float* gq = (const float*)d_in[6];
    const float* btq = (const float*)d_in[7];
    const float* gk = (const float*)d_in[8];
    const float* btk = (const float*)d_in[9];
    float* out = (float*)d_out;

    short* a1 = (short*)d_ws;                          // [8192][1024] bf16
    short* a2 = a1 + (size_t)ROWS * CDIM;
    short* wqT = a2 + (size_t)ROWS * CDIM;             // [1024][1024]
    short* wkvT = wqT + (size_t)CDIM * CDIM;           // [2048][1024]
    short* qln = wkvT + (size_t)2 * CDIM * CDIM;       // [B][H][N][64]
    short* kln = qln + (size_t)ROWS * CDIM;            // [B][H][N][64]
    short* vt = kln + (size_t)ROWS * CDIM;             // [B][H][64][N]

    const int n8 = ROWS * CDIM / 8;
    cvt_bf16<<<dim3(n8 / 256), 256, 0, stream>>>(x1, a1, n8);
    cvt_bf16<<<dim3(n8 / 256), 256, 0, stream>>>(x2, a2, n8);
    wtrans<<<dim3(16, 16), 256, 0, stream>>>(wq, wqT, CDIM);
    wtrans<<<dim3(32, 16), 256, 0, stream>>>(wkv, wkvT, 2 * CDIM);

    gemm_q_ln<<<dim3(8, 64), 256, 0, stream>>>(a1, wqT, bq, gq, btq, qln);
    gemm_kv<<<dim3(16, 64), 256, 0, stream>>>(a2, wkvT, bkv, gk, btk, kln, vt);
    attn_fa<<<dim3(64, 32), 256, 0, stream>>>(qln, kln, vt, out);
}